// Round 1
// baseline (1046.312 us; speedup 1.0000x reference)
//
#include <hip/hip_runtime.h>

#define BATCH 512
#define SEQ   1024
#define NT    64
#define BPW   16                 // batches per wave
#define NBLK  (BATCH / BPW)      // 32 blocks x 1 wave
#define CH    4                  // steps per staged chunk
#define NCH   (SEQ / CH)         // 256

typedef float    f32x4 __attribute__((ext_vector_type(4)));
typedef _Float16 v8h   __attribute__((ext_vector_type(8)));
typedef int      int4v __attribute__((ext_vector_type(4)));
typedef int      int2v __attribute__((ext_vector_type(2)));

__device__ __forceinline__ int pkrtz_bits(float a, float b) {
    auto pk = __builtin_amdgcn_cvt_pkrtz(a, b);
    return __builtin_bit_cast(int, pk);
}

__device__ __forceinline__ float exp2_hw(float x) {
    float r; asm("v_exp_f32 %0, %1" : "=v"(r) : "v"(x)); return r;
}
__device__ __forceinline__ float log2_hw(float x) {
    float r; asm("v_log_f32 %0, %1" : "=v"(r) : "v"(x)); return r;
}

// max with a DPP row-rotated copy (row = 16 lanes). ctrl: 0x120+n = row_ror:n
#define DPP_MAX(x, ctrl) { \
    int _t = __builtin_amdgcn_update_dpp( \
        __builtin_bit_cast(int, (x)), __builtin_bit_cast(int, (x)), \
        (ctrl), 0xf, 0xf, false); \
    (x) = fmaxf((x), __builtin_bit_cast(float, _t)); }

#define GLDS16(gsrc, ldst) \
    __builtin_amdgcn_global_load_lds( \
        (const __attribute__((address_space(1))) unsigned int*)(gsrc), \
        (__attribute__((address_space(3))) unsigned int*)(ldst), 16, 0, 0)
#define GLDS4(gsrc, ldst) \
    __builtin_amdgcn_global_load_lds( \
        (const __attribute__((address_space(1))) unsigned int*)(gsrc), \
        (__attribute__((address_space(3))) unsigned int*)(ldst), 4, 0, 0)

// 16 batches per wave via mfma_f32_16x16x32_f16.
// dp kept in log2 domain. Recurrence (exact for ANY wave-uniform msh):
//   dp2_new[m][j] = em[m][j] + log2( sum_i 2^(dp2[m][i]-msh[m]) * E[i][j] )
//   em = e*INVLN2 + msh ; E = exp(trans) in f16 (pkrtz, same numerics as the
//   429us kernel). msh[m] = EXACT per-batch max of dp2, one step stale,
//   computed by a 4-stage DPP row_ror butterfly (off the critical path).
//   Safety: step growth of max <= (ln(64*1.11)+|e|max)*1.4427 ~= 14.9 < 15.98
//   => w = 2^(dp2-msh) <= 2^14.9 < f16 max. Underflowed terms are negligible.
// Layout conventions (self-consistent A/B contraction-permutation):
//   C/D (m89-verified): col=lane&15 (=cc), row=4*(lane>>4)+reg (=m).
//   Tile v covers tags j = 4*cc + v  -> per-lane e_t read is one b128.
//   A-frag: row m=cc, k = 32h+8q+e.  B-frag: col cc, same k; B[k][j]=E[k][j].
//   w LDS buffer: row m (128B), slot k at byte 2k, XOR-swizzled by ((m&7)<<4)
//   -> conflict-free b64 writes, 2-way (free) b128 reads.
__global__ __launch_bounds__(64, 1) void crf_kernel(
        const float* __restrict__ emis,
        const int*   __restrict__ tags,
        const float* __restrict__ mask,
        const float* __restrict__ trans,
        float*       __restrict__ out)
{
    const int b0 = blockIdx.x * BPW;
    const int l  = threadIdx.x;
    const int cc = l & 15;
    const int q  = l >> 4;

    __shared__ float estage[2][BPW * CH * NT];           // 2 x 16 KB
    __shared__ float mstage[2][BPW * CH];                // 2 x 256 B
    __shared__ __align__(16) short wbuf[BPW * NT];       // 2 KB (f16 w)
    __shared__ float zbuf[BPW * NT];                     // 4 KB
    __shared__ float zarr[BPW];

    // ---- B fragments: Bf[v][h] = E[k][4*cc+v], k = 32h+8q+e ----
    v8h Bf[4][2];
    #pragma unroll
    for (int v = 0; v < 4; ++v) {
        #pragma unroll
        for (int h = 0; h < 2; ++h) {
            int pk[4];
            #pragma unroll
            for (int r = 0; r < 4; ++r) {
                const int k0 = 32*h + 8*q + 2*r;
                const float f0 = __expf(trans[k0*NT + 4*cc + v]);
                const float f1 = __expf(trans[(k0+1)*NT + 4*cc + v]);
                pk[r] = pkrtz_bits(f0, f1);
            }
            int4v pv = { pk[0], pk[1], pk[2], pk[3] };
            Bf[v][h] = __builtin_bit_cast(v8h, pv);
        }
    }

    // ---- fixed per-lane LDS byte addresses for the w round trip ----
    int waddr[4];
    #pragma unroll
    for (int rr = 0; rr < 4; ++rr) {
        const int m = 4*q + rr;
        waddr[rr] = m*128 + ((8*cc) ^ ((m & 7) << 4));
    }
    const int raddr0 = cc*128 + ((16*q)      ^ ((cc & 7) << 4));
    const int raddr1 = cc*128 + ((64 + 16*q) ^ ((cc & 7) << 4));

    const float* eb = emis + (size_t)b0 * SEQ * NT;

    // ---- stage chunk 0 (16 + 1 DMA ops) ----
    #pragma unroll
    for (int m = 0; m < BPW; ++m)
        GLDS16(eb + (size_t)m*SEQ*NT + l*4, &estage[0][m*CH*NT]);
    GLDS4(mask + (size_t)(b0 + (l >> 2))*SEQ + (l & 3), &mstage[0][0]);

    float dpc[4][4] = {{0,0,0,0},{0,0,0,0},{0,0,0,0},{0,0,0,0}};
    float msh[4] = {0.f, 0.f, 0.f, 0.f};

    const float INVLN2 = 1.44269504088896340736f;
    const float LN2    = 0.69314718055994530942f;
    const f32x4 zero4  = {0.f, 0.f, 0.f, 0.f};

    for (int ch = 0; ch < NCH; ++ch) {
        const int buf = ch & 1;
        if (ch + 1 < NCH) {
            #pragma unroll
            for (int m = 0; m < BPW; ++m)
                GLDS16(eb + (size_t)m*SEQ*NT + (ch+1)*CH*NT + l*4,
                       &estage[buf ^ 1][m*CH*NT]);
            GLDS4(mask + (size_t)(b0 + (l >> 2))*SEQ + (ch+1)*CH + (l & 3),
                  &mstage[buf ^ 1][0]);
            asm volatile("s_waitcnt vmcnt(17)" ::: "memory");   // chunk ch landed
        } else {
            asm volatile("s_waitcnt vmcnt(0)" ::: "memory");
        }

        #pragma unroll
        for (int ts = 0; ts < CH; ++ts) {
            // emissions (one b128 per batch-group) + mask (uniform broadcast)
            f32x4 ev[4]; float mk[4];
            #pragma unroll
            for (int rr = 0; rr < 4; ++rr) {
                ev[rr] = *(const f32x4*)&estage[buf][(4*q+rr)*CH*NT + ts*NT + 4*cc];
                mk[rr] = mstage[buf][(4*q+rr)*CH + ts];
            }
            float em[4][4];
            #pragma unroll
            for (int rr = 0; rr < 4; ++rr) {
                #pragma unroll
                for (int v = 0; v < 4; ++v)
                    em[rr][v] = fmaf(ev[rr][v], INVLN2, msh[rr]);
            }

            // w = 2^(dp2 - msh) -> f16 pairs -> swizzled b64 writes
            #pragma unroll
            for (int rr = 0; rr < 4; ++rr) {
                const float w0 = exp2_hw(dpc[rr][0] - msh[rr]);
                const float w1 = exp2_hw(dpc[rr][1] - msh[rr]);
                const float w2 = exp2_hw(dpc[rr][2] - msh[rr]);
                const float w3 = exp2_hw(dpc[rr][3] - msh[rr]);
                int2v pw = { pkrtz_bits(w0, w1), pkrtz_bits(w2, w3) };
                *(int2v*)((char*)wbuf + waddr[rr]) = pw;
            }

            // next-step msh: exact per-batch max of CURRENT dp (used at t+1)
            float nmax[4];
            #pragma unroll
            for (int rr = 0; rr < 4; ++rr)
                nmax[rr] = fmaxf(fmaxf(dpc[rr][0], dpc[rr][1]),
                                 fmaxf(dpc[rr][2], dpc[rr][3]));

            // A fragments (same-wave LDS is in-order: reads see the writes)
            const int4v a0 = *(const int4v*)((const char*)wbuf + raddr0);
            const int4v a1 = *(const int4v*)((const char*)wbuf + raddr1);
            const v8h A0 = __builtin_bit_cast(v8h, a0);
            const v8h A1 = __builtin_bit_cast(v8h, a1);

            f32x4 acc[4];
            #pragma unroll
            for (int v = 0; v < 4; ++v) {
                acc[v] = __builtin_amdgcn_mfma_f32_16x16x32_f16(A0, Bf[v][0], zero4, 0, 0, 0);
                acc[v] = __builtin_amdgcn_mfma_f32_16x16x32_f16(A1, Bf[v][1], acc[v], 0, 0, 0);
            }

            // DPP row-max butterfly (pure VALU, fills MFMA/LDS shadow)
            #pragma unroll
            for (int rr = 0; rr < 4; ++rr) {
                DPP_MAX(nmax[rr], 0x128)   // row_ror:8
                DPP_MAX(nmax[rr], 0x124)   // row_ror:4
                DPP_MAX(nmax[rr], 0x122)   // row_ror:2
                DPP_MAX(nmax[rr], 0x121)   // row_ror:1
            }

            // dp2 update (mask blend is linear in log2 domain too)
            #pragma unroll
            for (int rr = 0; rr < 4; ++rr) {
                #pragma unroll
                for (int v = 0; v < 4; ++v) {
                    const float dpn = log2_hw(acc[v][rr]) + em[rr][v];
                    dpc[rr][v] = fmaf(mk[rr], dpn - dpc[rr][v], dpc[rr][v]);
                }
            }

            #pragma unroll
            for (int rr = 0; rr < 4; ++rr) msh[rr] = nmax[rr];
        }
    }

    // ---- z[m] = LN2 * log2sumexp2_j dp2[m][j] ----
    #pragma unroll
    for (int rr = 0; rr < 4; ++rr) {
        f32x4 dv = { dpc[rr][0], dpc[rr][1], dpc[rr][2], dpc[rr][3] };
        *(f32x4*)&zbuf[(4*q+rr)*NT + 4*cc] = dv;
    }
    if (l < BPW) {
        float mx = -3.0e38f;
        #pragma unroll 8
        for (int jj = 0; jj < NT; ++jj) mx = fmaxf(mx, zbuf[l*NT + jj]);
        float s = 0.f;
        #pragma unroll 8
        for (int jj = 0; jj < NT; ++jj) s += exp2_hw(zbuf[l*NT + jj] - mx);
        zarr[l] = LN2 * (mx + log2_hw(s));
    }

    // ---- gold scores for our 16 batches ----
    float tot = 0.f;
    for (int m = 0; m < BPW; ++m) {
        const int bb = b0 + m;
        const int*   tb  = tags + (size_t)bb * SEQ;
        const float* ebm = emis + (size_t)bb * SEQ * NT;
        const float* mbm = mask + (size_t)bb * SEQ;
        float acc = 0.f;
        for (int s = 1 + l; s < SEQ; s += 64) {
            const int tc = tb[s];
            const int tp = tb[s - 1];
            acc += (ebm[s*NT + tc] + trans[tp*NT + tc]) * mbm[s];
        }
        #pragma unroll
        for (int off = 32; off >= 1; off >>= 1)
            acc += __shfl_xor(acc, off, 64);
        tot += acc;
    }

    float zs = (l < BPW) ? zarr[l] : 0.f;
    #pragma unroll
    for (int off = 32; off >= 1; off >>= 1)
        zs += __shfl_xor(zs, off, 64);

    if (l == 0)
        atomicAdd(out, (tot - zs) * (1.0f / BATCH));
}

__global__ void zero_kernel(float* out) { if (threadIdx.x == 0) out[0] = 0.0f; }

extern "C" void kernel_launch(void* const* d_in, const int* in_sizes, int n_in,
                              void* d_out, int out_size, void* d_ws, size_t ws_size,
                              hipStream_t stream) {
    const float* emis  = (const float*)d_in[0];
    const int*   tags  = (const int*)d_in[1];
    const float* mask  = (const float*)d_in[2];
    const float* trans = (const float*)d_in[3];
    float* out = (float*)d_out;

    zero_kernel<<<1, 64, 0, stream>>>(out);
    crf_kernel<<<NBLK, 64, 0, stream>>>(emis, tags, mask, trans, out);
}

// Round 2
// 466.898 us; speedup vs baseline: 2.2410x; 2.2410x over previous
//
#include <hip/hip_runtime.h>

#define BATCH 512
#define SEQ   1024
#define NT    64
#define NSEG  8
#define SEGLEN (SEQ / NSEG)   // 128
#define CH    4
#define NCHS  (SEGLEN / CH)   // 32

typedef float    f32x4 __attribute__((ext_vector_type(4)));
typedef _Float16 v8h   __attribute__((ext_vector_type(8)));
typedef _Float16 h2v   __attribute__((ext_vector_type(2)));
typedef int      int4v __attribute__((ext_vector_type(4)));

__device__ __forceinline__ int pkrtz_bits(float a, float b) {
    auto pk = __builtin_amdgcn_cvt_pkrtz(a, b);   // lo=a, hi=b
    return __builtin_bit_cast(int, pk);
}
__device__ __forceinline__ float exp2_hw(float x) {
    float r; asm("v_exp_f32 %0, %1" : "=v"(r) : "v"(x)); return r;
}
__device__ __forceinline__ float log2_hw(float x) {
    float r; asm("v_log_f32 %0, %1" : "=v"(r) : "v"(x)); return r;
}
// row_ror:n reductions within 16-lane rows (verified pattern from round-1 pass)
#define DPP_MAX(x, ctrl) { int _t = __builtin_amdgcn_update_dpp( \
    __builtin_bit_cast(int,(x)), __builtin_bit_cast(int,(x)), (ctrl), 0xf, 0xf, false); \
    (x) = fmaxf((x), __builtin_bit_cast(float,_t)); }
#define DPP_ADD(x, ctrl) { int _t = __builtin_amdgcn_update_dpp( \
    __builtin_bit_cast(int,(x)), __builtin_bit_cast(int,(x)), (ctrl), 0xf, 0xf, false); \
    (x) += __builtin_bit_cast(float,_t); }

// Segmented matrix-product scan for the CRF partition function.
//
// v^T_final = 1^T * PROD_t (E*diag(exp e_t)),  Z = log(sum v_final).
// Per batch: 8 waves, each computes G_s = (PROD_{t in seg} E_hat_t)^T via
//   G <- (D_t E^T) * G   (D_t = diag(2^(e_t/ln2 - r_t)), r_t = rescale)
// entirely in registers:
//  - A = E^T row-scaled per step (static f16 frags * per-row 2^ scale)
//  - B = G as f16 fragments; the k-axis is RELABELED by
//        rho(h,q,e) = 16*(2h+(e>>2)) + 4q + (e&3)
//    (baked into the static A frags) so that the MFMA C-layout accumulator
//    repacks into next step's B fragments with 32 in-lane cvt_pkrtz —
//    NO LDS round trip in the recurrence.
//  - rescale governor: r_t = emax_t*INVLN2 + 6.2 + 0.5*log2(M_{t-2}),
//    M = exact max(acc) (max3 tree + 6 shfl, off the critical path by 2 steps).
//    Damped (poles 0.707) => f16 state stays ~2^[-14, +4]. ls accumulates r_t.
// Phase 2 (in-block): barrier, wave0 chains u <- G_s u in log2 domain,
// Z = ln2*(LSE2(du) + sum ls). Gold scores by all 512 threads.
__global__ __launch_bounds__(512, 1) void crf_kernel(
        const float* __restrict__ emis,
        const int*   __restrict__ tags,
        const float* __restrict__ mask,
        const float* __restrict__ trans,
        float*       __restrict__ out)
{
    const int b   = blockIdx.x;
    const int tid = threadIdx.x;
    const int seg = tid >> 6;
    const int l   = tid & 63;
    const int cc  = l & 15;
    const int q   = l >> 4;

    __shared__ _Float16 gseg[(NSEG - 1) * NT * NT];  // 56 KB: segment matrices 1..7
    __shared__ float ubuf[NT];
    __shared__ float lsarr[NSEG];
    __shared__ float gred[NSEG];
    __shared__ float zsh;

    const float INVLN2 = 1.44269504088896340736f;
    const float LN2    = 0.69314718055994530942f;
    const float RSC    = 6.2f;   // upper bound of log2 col-sum growth (64*1.105)
    const f32x4 zero4  = {0.f, 0.f, 0.f, 0.f};

    // ---- static A fragments: A0[mt][h] holds E[rho(h,q,e)][16mt+cc] f16 pairs ----
    v8h A0[4][2];
    #pragma unroll
    for (int mt = 0; mt < 4; ++mt) {
        #pragma unroll
        for (int h = 0; h < 2; ++h) {
            int4v pv;
            #pragma unroll
            for (int r2 = 0; r2 < 4; ++r2) {
                const int row0 = 16 * (2*h + (r2 >> 1)) + 4*q + 2*(r2 & 1);
                const int colm = 16 * mt + cc;
                pv[r2] = pkrtz_bits(__expf(trans[row0 * NT + colm]),
                                    __expf(trans[(row0 + 1) * NT + colm]));
            }
            A0[mt][h] = __builtin_bit_cast(v8h, pv);
        }
    }

    // ---- B = G_0 = Identity, directly in fragment form ----
    v8h Bf[4][2];
    #pragma unroll
    for (int v = 0; v < 4; ++v) {
        #pragma unroll
        for (int h = 0; h < 2; ++h) {
            int4v pv;
            #pragma unroll
            for (int r2 = 0; r2 < 4; ++r2) {
                const int row0 = 16 * (2*h + (r2 >> 1)) + 4*q + 2*(r2 & 1);
                const int col  = 4 * cc + v;
                unsigned lo = (row0 == col)     ? 0x3C00u : 0u;
                unsigned hi = (row0 + 1 == col) ? 0x3C00u : 0u;
                pv[r2] = (int)(lo | (hi << 16));
            }
            Bf[v][h] = __builtin_bit_cast(v8h, pv);
        }
    }

    f32x4 acc[4][4];
    float ls = 0.0f, mlog1 = 0.0f, mlog2 = 0.0f;

    const float* ebase = emis + (size_t)b * SEQ * NT + (size_t)seg * SEGLEN * NT;
    const float* mbase = mask + (size_t)b * SEQ + seg * SEGLEN;

#define LOADCHUNK(c, E, MV) { \
    _Pragma("unroll") \
    for (int t2 = 0; t2 < CH; ++t2) { \
        _Pragma("unroll") \
        for (int mt = 0; mt < 4; ++mt) \
            E[t2*4 + mt] = ebase[((c)*CH + t2) * NT + 16*mt + cc]; } \
    MV = *(const f32x4*)(mbase + (c) * CH); }

#define STEP(E, MV, ts) { \
    const float e0 = E[(ts)*4+0], e1 = E[(ts)*4+1], e2 = E[(ts)*4+2], e3 = E[(ts)*4+3]; \
    const float mk = MV[ts]; \
    float em = fmaxf(fmaxf(e0, e1), fmaxf(e2, e3)); \
    DPP_MAX(em, 0x128) DPP_MAX(em, 0x124) DPP_MAX(em, 0x122) DPP_MAX(em, 0x121) \
    const float rs = fmaf(em, INVLN2, RSC + 0.5f * mlog2); \
    ls += rs; \
    int spk[4]; \
    spk[0] = pkrtz_bits(exp2_hw(fmaf(e0, INVLN2, -rs)), exp2_hw(fmaf(e0, INVLN2, -rs))); \
    spk[1] = pkrtz_bits(exp2_hw(fmaf(e1, INVLN2, -rs)), exp2_hw(fmaf(e1, INVLN2, -rs))); \
    spk[2] = pkrtz_bits(exp2_hw(fmaf(e2, INVLN2, -rs)), exp2_hw(fmaf(e2, INVLN2, -rs))); \
    spk[3] = pkrtz_bits(exp2_hw(fmaf(e3, INVLN2, -rs)), exp2_hw(fmaf(e3, INVLN2, -rs))); \
    _Pragma("unroll") \
    for (int mt = 0; mt < 4; ++mt) { \
        int4v sq = { spk[mt], spk[mt], spk[mt], spk[mt] }; \
        const v8h sv  = __builtin_bit_cast(v8h, sq); \
        const v8h As0 = A0[mt][0] * sv; \
        const v8h As1 = A0[mt][1] * sv; \
        _Pragma("unroll") \
        for (int v = 0; v < 4; ++v) \
            acc[mt][v] = __builtin_amdgcn_mfma_f32_16x16x32_f16(As1, Bf[v][1], \
                         __builtin_amdgcn_mfma_f32_16x16x32_f16(As0, Bf[v][0], zero4, 0,0,0), 0,0,0); \
    } \
    if (mk != 1.0f) {  /* generic mask blend (never taken for all-ones mask) */ \
        const float g2 = exp2_hw(-rs), om = 1.0f - mk; \
        _Pragma("unroll") \
        for (int v = 0; v < 4; ++v) { \
            _Pragma("unroll") \
            for (int h = 0; h < 2; ++h) { \
                const int4v bb = __builtin_bit_cast(int4v, Bf[v][h]); \
                _Pragma("unroll") \
                for (int r2 = 0; r2 < 4; ++r2) { \
                    const int mt = 2*h + (r2 >> 1), rr = 2*(r2 & 1); \
                    const h2v gh = __builtin_bit_cast(h2v, bb[r2]); \
                    acc[mt][v][rr]   = mk * acc[mt][v][rr]   + om * g2 * (float)gh.x; \
                    acc[mt][v][rr+1] = mk * acc[mt][v][rr+1] + om * g2 * (float)gh.y; \
                } } } } \
    float M = 0.0f; \
    _Pragma("unroll") \
    for (int mt = 0; mt < 4; ++mt) { \
        _Pragma("unroll") \
        for (int v = 0; v < 4; ++v) { \
            const f32x4 a = acc[mt][v]; \
            M = fmaxf(M, fmaxf(fmaxf(a.x, a.y), fmaxf(a.z, a.w))); } } \
    M = fmaxf(M, __shfl_xor(M, 32, 64)); M = fmaxf(M, __shfl_xor(M, 16, 64)); \
    M = fmaxf(M, __shfl_xor(M,  8, 64)); M = fmaxf(M, __shfl_xor(M,  4, 64)); \
    M = fmaxf(M, __shfl_xor(M,  2, 64)); M = fmaxf(M, __shfl_xor(M,  1, 64)); \
    mlog2 = mlog1; mlog1 = log2_hw(M); \
    _Pragma("unroll") \
    for (int v = 0; v < 4; ++v) { \
        _Pragma("unroll") \
        for (int h = 0; h < 2; ++h) { \
            int4v nb; \
            _Pragma("unroll") \
            for (int r2 = 0; r2 < 4; ++r2) { \
                const int mt = 2*h + (r2 >> 1), rr = 2*(r2 & 1); \
                nb[r2] = pkrtz_bits(acc[mt][v][rr], acc[mt][v][rr+1]); } \
            Bf[v][h] = __builtin_bit_cast(v8h, nb); } } }

    float eA[16], eB[16];
    f32x4 mA, mB;
    LOADCHUNK(0, eA, mA);
    #pragma unroll 1
    for (int c = 0; c < NCHS; c += 2) {
        LOADCHUNK(c + 1, eB, mB);
        STEP(eA, mA, 0) STEP(eA, mA, 1) STEP(eA, mA, 2) STEP(eA, mA, 3)
        if (c + 2 < NCHS) LOADCHUNK(c + 2, eA, mA);
        STEP(eB, mB, 0) STEP(eB, mB, 1) STEP(eB, mB, 2) STEP(eB, mB, 3)
    }

    // ---- phase-1 epilogue: publish segment results ----
    if (seg > 0) {
        _Float16* gp = &gseg[(seg - 1) * NT * NT];
        #pragma unroll
        for (int v = 0; v < 4; ++v) {
            #pragma unroll
            for (int h = 0; h < 2; ++h) {
                const int4v bb = __builtin_bit_cast(int4v, Bf[v][h]);
                #pragma unroll
                for (int r2 = 0; r2 < 4; ++r2) {
                    const int row0 = 16 * (2*h + (r2 >> 1)) + 4*q + 2*(r2 & 1);
                    const int col  = 4 * cc + v;
                    *(int*)((char*)gp + (size_t)(col * NT + row0) * 2) = bb[r2];
                }
            }
        }
    } else {
        // wave 0: u0 = G_0 * 1  (row sums of acc), published to ubuf
        #pragma unroll
        for (int mt = 0; mt < 4; ++mt) {
            #pragma unroll
            for (int r = 0; r < 4; ++r) {
                float rsum = acc[mt][0][r] + acc[mt][1][r] + acc[mt][2][r] + acc[mt][3][r];
                DPP_ADD(rsum, 0x128) DPP_ADD(rsum, 0x124) DPP_ADD(rsum, 0x122) DPP_ADD(rsum, 0x121)
                if (cc == 0) ubuf[16*mt + 4*q + r] = rsum;
            }
        }
    }
    if (l == 0) lsarr[seg] = ls;

    __syncthreads();

    // ---- phase 2a: wave 0 chains u <- G_s u (log2 domain) ----
    if (seg == 0) {
        float du = log2_hw(ubuf[l]);
        #pragma unroll 1
        for (int s = 1; s < NSEG; ++s) {
            float mu = du;
            mu = fmaxf(mu, __shfl_xor(mu, 32, 64)); mu = fmaxf(mu, __shfl_xor(mu, 16, 64));
            mu = fmaxf(mu, __shfl_xor(mu,  8, 64)); mu = fmaxf(mu, __shfl_xor(mu,  4, 64));
            mu = fmaxf(mu, __shfl_xor(mu,  2, 64)); mu = fmaxf(mu, __shfl_xor(mu,  1, 64));
            ubuf[l] = exp2_hw(du - mu);
            const _Float16* gp = &gseg[(s - 1) * NT * NT];
            float S = 0.0f;
            #pragma unroll 8
            for (int j = 0; j < NT; ++j)
                S = fmaf((float)gp[j * NT + l], ubuf[j], S);
            du = mu + log2_hw(S);
        }
        float mu = du;
        mu = fmaxf(mu, __shfl_xor(mu, 32, 64)); mu = fmaxf(mu, __shfl_xor(mu, 16, 64));
        mu = fmaxf(mu, __shfl_xor(mu,  8, 64)); mu = fmaxf(mu, __shfl_xor(mu,  4, 64));
        mu = fmaxf(mu, __shfl_xor(mu,  2, 64)); mu = fmaxf(mu, __shfl_xor(mu,  1, 64));
        float se = exp2_hw(du - mu);
        se += __shfl_xor(se, 32, 64); se += __shfl_xor(se, 16, 64);
        se += __shfl_xor(se,  8, 64); se += __shfl_xor(se,  4, 64);
        se += __shfl_xor(se,  2, 64); se += __shfl_xor(se,  1, 64);
        float LStot = 0.0f;
        #pragma unroll
        for (int s = 0; s < NSEG; ++s) LStot += lsarr[s];
        const float Z = LN2 * (mu + log2_hw(se) + LStot);
        if (l == 0) zsh = Z;
    }

    // ---- phase 2b: gold scores (all 512 threads) ----
    {
        const int*   tb  = tags + (size_t)b * SEQ;
        const float* ebm = emis + (size_t)b * SEQ * NT;
        const float* mbm = mask + (size_t)b * SEQ;
        float acg = 0.0f;
        for (int s = 1 + tid; s < SEQ; s += NSEG * 64) {
            const int tc = tb[s];
            const int tp = tb[s - 1];
            acg += (ebm[(size_t)s * NT + tc] + trans[tp * NT + tc]) * mbm[s];
        }
        acg += __shfl_xor(acg, 32, 64); acg += __shfl_xor(acg, 16, 64);
        acg += __shfl_xor(acg,  8, 64); acg += __shfl_xor(acg,  4, 64);
        acg += __shfl_xor(acg,  2, 64); acg += __shfl_xor(acg,  1, 64);
        if (l == 0) gred[seg] = acg;
    }

    __syncthreads();

    if (tid == 0) {
        float tot = 0.0f;
        #pragma unroll
        for (int s = 0; s < NSEG; ++s) tot += gred[s];
        atomicAdd(out, (tot - zsh) * (1.0f / BATCH));
    }
}

__global__ void zero_kernel(float* out) { if (threadIdx.x == 0) out[0] = 0.0f; }

extern "C" void kernel_launch(void* const* d_in, const int* in_sizes, int n_in,
                              void* d_out, int out_size, void* d_ws, size_t ws_size,
                              hipStream_t stream) {
    const float* emis  = (const float*)d_in[0];
    const int*   tags  = (const int*)d_in[1];
    const float* mask  = (const float*)d_in[2];
    const float* trans = (const float*)d_in[3];
    float* out = (float*)d_out;

    zero_kernel<<<1, 64, 0, stream>>>(out);
    crf_kernel<<<BATCH, NSEG * 64, 0, stream>>>(emis, tags, mask, trans, out);
}